// Round 10
// baseline (246.269 us; speedup 1.0000x reference)
//
#include <hip/hip_runtime.h>

// RGCN 2-layer, N=100000, E=3200000, R=8, H=C=16.
// Partition redesign (r10): all per-block global-atomic flushes capped at
// <=49 bins. chist(49) -> cscan -> part1(coarse scatter) -> fhist(32 bins
// per coarse slice) -> fscan -> part2(two-pass per coarse slice, 32-bin
// LDS rank, 32 global atomics/block). Layer kernels identical to round 9:
// Phase A (node,rel) counting sort in LDS; Phase B segmented sums via
// indicator-MFMA over 32-edge batches; Phase C 4 rel-block MFMAs + root
// MFMA + fused relu / log_softmax. All X gathers bf16 (L2-resident table).

constexpr int NN = 100000;
constexpr int NE = 3200000;
constexpr int NFINE = 1563;    // ceil(NN/64)
constexpr int NCOARSE = 49;    // ceil(NN/2048)
constexpr int NSLICE = 16;     // slices per coarse segment (part2/fhist)
constexpr int CAP = 3072;      // LDS edge capacity/bucket (mean 2048, sigma 45)
constexpr int SST = 136;       // S node stride (ushorts); 272B = 16B-aligned rows

typedef short bf16x8 __attribute__((ext_vector_type(8)));
typedef float f32x4 __attribute__((ext_vector_type(4)));

__device__ __forceinline__ short f2bf(float f) {
  union { float f; unsigned u; } v; v.f = f;
  unsigned r = v.u + 0x7FFFu + ((v.u >> 16) & 1u);  // RNE
  return (short)(r >> 16);
}

// K0: embed f32 -> bf16 table (once).
__global__ void __launch_bounds__(256) conv_kernel(
    const float* __restrict__ X, unsigned short* __restrict__ Xb) {
  int i = blockIdx.x * 256 + threadIdx.x;
  if (i < NN * 4) {
    float4 v = reinterpret_cast<const float4*>(X)[i];
    ushort4 o;
    o.x = (unsigned short)f2bf(v.x); o.y = (unsigned short)f2bf(v.y);
    o.z = (unsigned short)f2bf(v.z); o.w = (unsigned short)f2bf(v.w);
    reinterpret_cast<ushort4*>(Xb)[i] = o;
  }
}

// K1: coarse histogram (dst>>11), 49-bin LDS, 49 flush atomics/block.
__global__ void __launch_bounds__(256) chist_kernel(
    const int* __restrict__ dst, unsigned* __restrict__ ccnt) {
  __shared__ unsigned h[NCOARSE];
  if (threadIdx.x < NCOARSE) h[threadIdx.x] = 0u;
  __syncthreads();
  const int base = blockIdx.x * 8192;
#pragma unroll
  for (int i = 0; i < 32; ++i) {
    int e = base + i * 256 + threadIdx.x;
    if (e < NE) atomicAdd(&h[(unsigned)dst[e] >> 11], 1u);
  }
  __syncthreads();
  if (threadIdx.x < NCOARSE && h[threadIdx.x])
    atomicAdd(&ccnt[threadIdx.x], h[threadIdx.x]);
}

// K2: 1-wave shfl scan of 49 coarse counts -> cbnd[0..49], ccur.
__global__ void __launch_bounds__(64) cscan_kernel(
    const unsigned* __restrict__ ccnt, unsigned* __restrict__ cbnd,
    unsigned* __restrict__ ccur) {
  int t = threadIdx.x;
  unsigned v = (t < NCOARSE) ? ccnt[t] : 0u;
  unsigned incl = v;
#pragma unroll
  for (int d = 1; d < 64; d <<= 1) {
    unsigned u = __shfl_up(incl, d, 64);
    if (t >= d) incl += u;
  }
  unsigned excl = incl - v;
  if (t <= NCOARSE) cbnd[t] = excl;   // cbnd[49] = NE (lane 49: v=0)
  if (t < NCOARSE) ccur[t] = excl;
}

// K3: coarse partition (dst>>11). Entry = src | rel<<17 | (dst&2047)<<20.
__global__ void __launch_bounds__(256) part1_kernel(
    const int* __restrict__ src, const int* __restrict__ dst,
    const int* __restrict__ typ, unsigned* __restrict__ ccur,
    unsigned* __restrict__ buf1) {
  __shared__ unsigned hist[NCOARSE];
  __shared__ unsigned gb[NCOARSE];
  if (threadIdx.x < NCOARSE) hist[threadIdx.x] = 0u;
  __syncthreads();
  const int base = blockIdx.x * 4096;
  unsigned ent[16], cb[16], rk[16];
#pragma unroll
  for (int i = 0; i < 16; ++i) {
    int e = base + i * 256 + threadIdx.x;
    if (e < NE) {
      unsigned d = (unsigned)dst[e];
      ent[i] = (unsigned)src[e] | ((unsigned)typ[e] << 17) | ((d & 2047u) << 20);
      cb[i] = d >> 11;
      rk[i] = atomicAdd(&hist[cb[i]], 1u);
    } else cb[i] = 0xFFFFFFFFu;
  }
  __syncthreads();
  if (threadIdx.x < NCOARSE && hist[threadIdx.x])
    gb[threadIdx.x] = atomicAdd(&ccur[threadIdx.x], hist[threadIdx.x]);
  __syncthreads();
#pragma unroll
  for (int i = 0; i < 16; ++i)
    if (cb[i] != 0xFFFFFFFFu) buf1[gb[cb[i]] + rk[i]] = ent[i];
}

// K4: fine histogram from buf1 per coarse slice: 32-bin LDS, 32 flushes.
// Global fine id of entry e in coarse c: c*32 + ((e>>26)&31) == dst>>6.
__global__ void __launch_bounds__(256) fhist_kernel(
    const unsigned* __restrict__ buf1, const unsigned* __restrict__ cbnd,
    unsigned* __restrict__ fcnt) {
  __shared__ unsigned h[32];
  const int c = blockIdx.x / NSLICE, s = blockIdx.x % NSLICE;
  const unsigned b0 = cbnd[c], b1 = cbnd[c + 1];
  const unsigned len = b1 - b0, sl = (len + NSLICE - 1) / NSLICE;
  const unsigned lo = b0 + s * sl;
  const unsigned hi = (lo + sl < b1) ? (lo + sl) : b1;
  if (threadIdx.x < 32) h[threadIdx.x] = 0u;
  __syncthreads();
  for (unsigned p = lo + threadIdx.x; p < hi; p += 256)
    atomicAdd(&h[(buf1[p] >> 26) & 31u], 1u);
  __syncthreads();
  if (threadIdx.x < 32 && h[threadIdx.x])
    atomicAdd(&fcnt[c * 32 + threadIdx.x], h[threadIdx.x]);
}

// K5: exclusive scan of fcnt -> foff[0..NFINE], fine cursors.
__global__ void __launch_bounds__(256) fscan_kernel(
    const unsigned* __restrict__ fcnt, unsigned* __restrict__ foff,
    unsigned* __restrict__ fcur) {
  __shared__ unsigned sh[256];
  unsigned v[7], s = 0;
#pragma unroll
  for (int j = 0; j < 7; ++j) {
    int idx = threadIdx.x * 7 + j;
    v[j] = (idx < NFINE) ? fcnt[idx] : 0u;
    s += v[j];
  }
  sh[threadIdx.x] = s;
  __syncthreads();
  for (int d = 1; d < 256; d <<= 1) {
    unsigned t = (threadIdx.x >= d) ? sh[threadIdx.x - d] : 0u;
    __syncthreads();
    sh[threadIdx.x] += t;
    __syncthreads();
  }
  unsigned run = sh[threadIdx.x] - s;
#pragma unroll
  for (int j = 0; j < 7; ++j) {
    int idx = threadIdx.x * 7 + j;
    if (idx <= NFINE) foff[idx] = run;
    if (idx < NFINE) fcur[idx] = run;
    run += v[j];
  }
}

// K6: fine scatter, two passes over an L2-resident coarse slice.
// Pass1: 32-bin local hist + ONE fcur grab per bin. Pass2: re-read,
// LDS-rank, write low-26-bit entry to buf2.
__global__ void __launch_bounds__(256) part2_kernel(
    const unsigned* __restrict__ buf1, const unsigned* __restrict__ cbnd,
    unsigned* __restrict__ fcur, unsigned* __restrict__ buf2) {
  __shared__ unsigned h[32], gb[32], cur[32];
  const int c = blockIdx.x / NSLICE, s = blockIdx.x % NSLICE;
  const unsigned b0 = cbnd[c], b1 = cbnd[c + 1];
  const unsigned len = b1 - b0, sl = (len + NSLICE - 1) / NSLICE;
  const unsigned lo = b0 + s * sl;
  const unsigned hi = (lo + sl < b1) ? (lo + sl) : b1;
  if (threadIdx.x < 32) { h[threadIdx.x] = 0u; cur[threadIdx.x] = 0u; }
  __syncthreads();
  for (unsigned p = lo + threadIdx.x; p < hi; p += 256)
    atomicAdd(&h[(buf1[p] >> 26) & 31u], 1u);
  __syncthreads();
  if (threadIdx.x < 32) {
    unsigned n = h[threadIdx.x];
    gb[threadIdx.x] = n ? atomicAdd(&fcur[c * 32 + threadIdx.x], n) : 0u;
  }
  __syncthreads();
  for (unsigned p = lo + threadIdx.x; p < hi; p += 256) {
    unsigned e = buf1[p];
    unsigned fl = (e >> 26) & 31u;
    unsigned pos = gb[fl] + atomicAdd(&cur[fl], 1u);
    buf2[pos] = e & 0x03FFFFFFu;
  }
}

// K7/K8: per-bucket layer (identical to round 9).
template <int MODE>
__global__ void __launch_bounds__(512) layer_kernel(
    const unsigned short* __restrict__ Xb, const float* __restrict__ W,
    const float* __restrict__ ROOT, const float* __restrict__ BIAS,
    const unsigned* __restrict__ foff, const unsigned* __restrict__ buf2,
    unsigned short* __restrict__ Hout, float* __restrict__ Fout) {
  __shared__ unsigned short S[64 * SST];
  __shared__ unsigned E[CAP];
  __shared__ unsigned cnt512[512];
  __shared__ unsigned cur512[512];
  __shared__ unsigned wsum[8];
  const int tid = threadIdx.x;

  cnt512[tid] = 0u;
#pragma unroll
  for (int i = 0; i < CAP / 512; ++i) E[tid + i * 512] = 0u;
  __syncthreads();

  const unsigned p0 = foff[blockIdx.x];
  const int seg = (int)(foff[blockIdx.x + 1] - p0);

  unsigned e_0 = 0xFFFFFFFFu, e_1 = 0xFFFFFFFFu, e_2 = 0xFFFFFFFFu,
           e_3 = 0xFFFFFFFFu, e_4 = 0xFFFFFFFFu, e_5 = 0xFFFFFFFFu;
  if (tid < seg)          e_0 = buf2[p0 + tid];
  if (tid + 512 < seg)    e_1 = buf2[p0 + tid + 512];
  if (tid + 1024 < seg)   e_2 = buf2[p0 + tid + 1024];
  if (tid + 1536 < seg)   e_3 = buf2[p0 + tid + 1536];
  if (tid + 2048 < seg)   e_4 = buf2[p0 + tid + 2048];
  if (tid + 2560 < seg)   e_5 = buf2[p0 + tid + 2560];
  auto BIN = [](unsigned e) -> unsigned { return (e >> 17) & 511u; };
  auto HB = [&](unsigned e) {
    if (e != 0xFFFFFFFFu) atomicAdd(&cnt512[BIN(e)], 1u);
  };
  HB(e_0); HB(e_1); HB(e_2); HB(e_3); HB(e_4); HB(e_5);
  __syncthreads();

  unsigned own = cnt512[tid];
  unsigned incl = own;
#pragma unroll
  for (int d = 1; d < 64; d <<= 1) {
    unsigned t = __shfl_up(incl, d, 64);
    if ((tid & 63) >= d) incl += t;
  }
  if ((tid & 63) == 63) wsum[tid >> 6] = incl;
  __syncthreads();
  unsigned pre = 0;
#pragma unroll
  for (int wv = 0; wv < 8; ++wv)
    pre += (wv < (tid >> 6)) ? wsum[wv] : 0u;
  cur512[tid] = pre + incl - own;
  __syncthreads();

  auto SC = [&](unsigned e) {
    if (e != 0xFFFFFFFFu) {
      unsigned pos = atomicAdd(&cur512[BIN(e)], 1u);
      if (pos < (unsigned)CAP) E[pos] = e;
    }
  };
  SC(e_0); SC(e_1); SC(e_2); SC(e_3); SC(e_4); SC(e_5);
  __syncthreads();

  const int w = tid >> 6;
  const int lane = tid & 63;
  const int rc = lane & 15;
  const int quad = lane >> 4;

  for (int pq = 0; pq < 4; ++pq) {
    const int pp = w * 4 + pq;
    const int pb = pp * 16;
    const int beg = (int)(cur512[pb] - cnt512[pb]);
    const int end = (int)cur512[pb + 15];
    const unsigned rowbin = (unsigned)(pb + rc);

    f32x4 acc = {0.f, 0.f, 0.f, 0.f};
    int p = beg;
    for (; p + 32 <= end; p += 32) {
      bf16x8 af, bv;
#pragma unroll
      for (int j = 0; j < 8; ++j) {
        unsigned e = E[p + quad * 8 + j];
        af[j] = (((e >> 17) & 511u) == rowbin) ? (short)0x3F80 : (short)0;
        bv[j] = (short)Xb[(size_t)(e & 0x1FFFFu) * 16 + rc];
      }
      acc = __builtin_amdgcn_mfma_f32_16x16x32_bf16(af, bv, acc, 0, 0, 0);
    }
    if (p < end) {
      bf16x8 af, bv;
#pragma unroll
      for (int j = 0; j < 8; ++j) {
        int q = p + quad * 8 + j;
        unsigned e = E[q < CAP ? q : 0];
        bool v = q < end;
        af[j] = (v && ((e >> 17) & 511u) == rowbin) ? (short)0x3F80 : (short)0;
        bv[j] = (short)Xb[(size_t)(e & 0x1FFFFu) * 16 + rc];
      }
      acc = __builtin_amdgcn_mfma_f32_16x16x32_bf16(af, bv, acc, 0, 0, 0);
    }

#pragma unroll
    for (int r2 = 0; r2 < 4; ++r2) {
      int gbin = pb + quad * 4 + r2;
      unsigned ct = cnt512[gbin];
      float iv = 1.f / (float)(ct ? ct : 1u);
      int nd = gbin >> 3, rl = gbin & 7;
      S[nd * SST + rl * 16 + rc] = (unsigned short)f2bf(acc[r2] * iv);
    }
  }
  __syncthreads();

  if (w >= 4) return;
  const int fc = lane & 15;
  const int g = lane >> 4;
  const int n0 = blockIdx.x * 64 + w * 16;

  bf16x8 b0, b1, b2, b3, brt;
#pragma unroll
  for (int j = 0; j < 8; ++j) {
    int kq = g * 8 + j; int rb = kq >> 4; int kk = kq & 15;
    b0[j] = f2bf(W[(rb + 0) * 256 + kk * 16 + fc]);
    b1[j] = f2bf(W[(rb + 2) * 256 + kk * 16 + fc]);
    b2[j] = f2bf(W[(rb + 4) * 256 + kk * 16 + fc]);
    b3[j] = f2bf(W[(rb + 6) * 256 + kk * 16 + fc]);
    brt[j] = (kq < 16) ? f2bf(ROOT[kq * 16 + fc]) : (short)0;
  }

  const int kk0 = (g & 1) * 8;
  const int rsel = g >> 1;
  const int dl16 = w * 16 + fc;
  bf16x8 a0, a1, a2, a3;
#define LDA(AM, M)                                                        \
  {                                                                       \
    const unsigned short* sp2 = S + dl16 * SST + (2 * (M) + rsel) * 16 + kk0; \
    AM = *reinterpret_cast<const bf16x8*>(sp2);                           \
  }
  LDA(a0, 0) LDA(a1, 1) LDA(a2, 2) LDA(a3, 3)
#undef LDA

  bf16x8 ar = {0, 0, 0, 0, 0, 0, 0, 0};
  if (g < 2) {
    int node = n0 + fc;
    if (node < NN)
      ar = *reinterpret_cast<const bf16x8*>(Xb + (size_t)node * 16 + g * 8);
  }

  const float bc = BIAS[fc];
  f32x4 acc = {bc, bc, bc, bc};
  acc = __builtin_amdgcn_mfma_f32_16x16x32_bf16(a0, b0, acc, 0, 0, 0);
  acc = __builtin_amdgcn_mfma_f32_16x16x32_bf16(a1, b1, acc, 0, 0, 0);
  acc = __builtin_amdgcn_mfma_f32_16x16x32_bf16(a2, b2, acc, 0, 0, 0);
  acc = __builtin_amdgcn_mfma_f32_16x16x32_bf16(a3, b3, acc, 0, 0, 0);
  acc = __builtin_amdgcn_mfma_f32_16x16x32_bf16(ar, brt, acc, 0, 0, 0);

  if (MODE == 0) {
#pragma unroll
    for (int r2 = 0; r2 < 4; ++r2) {
      int node = n0 + g * 4 + r2;
      if (node < NN)
        Hout[(size_t)node * 16 + fc] = (unsigned short)f2bf(fmaxf(acc[r2], 0.f));
    }
  } else {
#pragma unroll
    for (int r2 = 0; r2 < 4; ++r2) {
      int node = n0 + g * 4 + r2;
      float zv = acc[r2];
      float mx = zv;
      mx = fmaxf(mx, __shfl_xor(mx, 1));
      mx = fmaxf(mx, __shfl_xor(mx, 2));
      mx = fmaxf(mx, __shfl_xor(mx, 4));
      mx = fmaxf(mx, __shfl_xor(mx, 8));
      float sm = expf(zv - mx);
      sm += __shfl_xor(sm, 1);
      sm += __shfl_xor(sm, 2);
      sm += __shfl_xor(sm, 4);
      sm += __shfl_xor(sm, 8);
      if (node < NN)
        Fout[(size_t)node * 16 + fc] = zv - mx - logf(sm);
    }
  }
}

extern "C" void kernel_launch(void* const* d_in, const int* in_sizes, int n_in,
                              void* d_out, int out_size, void* d_ws, size_t ws_size,
                              hipStream_t stream) {
  const float* embed = (const float*)d_in[0];
  const float* W1    = (const float*)d_in[1];
  const float* root1 = (const float*)d_in[2];
  const float* b1    = (const float*)d_in[3];
  const float* W2    = (const float*)d_in[4];
  const float* root2 = (const float*)d_in[5];
  const float* b2    = (const float*)d_in[6];
  const int* eidx    = (const int*)d_in[7];
  const int* etyp    = (const int*)d_in[8];
  const int* src = eidx;
  const int* dst = eidx + NE;
  float* out = (float*)d_out;

  // ws (u32): fcnt[1600] ccnt[64] foff[1600] fcur[1600] cbnd[64] ccur[64]
  //           buf1[NE] buf2[NE]
  // buf1 (dead after part2) hosts: h (bf16, first 800K u32) and xb (bf16
  // embed, next 800K u32); remaining 1.6M u32 is OOB-read spare.
  unsigned* fcnt = (unsigned*)d_ws;
  unsigned* ccnt = fcnt + 1600;
  unsigned* foff = ccnt + 64;
  unsigned* fcur = foff + 1600;
  unsigned* cbnd = fcur + 1600;
  unsigned* ccur = cbnd + 64;
  unsigned* buf1 = ccur + 64;
  unsigned* buf2 = buf1 + NE;
  unsigned short* h  = (unsigned short*)buf1;
  unsigned short* xb = (unsigned short*)(buf1 + 800000);

  hipMemsetAsync(fcnt, 0, (1600 + 64) * 4, stream);   // fcnt + ccnt
  chist_kernel<<<391, 256, 0, stream>>>(dst, ccnt);
  cscan_kernel<<<1, 64, 0, stream>>>(ccnt, cbnd, ccur);
  part1_kernel<<<782, 256, 0, stream>>>(src, dst, etyp, ccur, buf1);
  fhist_kernel<<<NCOARSE * NSLICE, 256, 0, stream>>>(buf1, cbnd, fcnt);
  fscan_kernel<<<1, 256, 0, stream>>>(fcnt, foff, fcur);
  part2_kernel<<<NCOARSE * NSLICE, 256, 0, stream>>>(buf1, cbnd, fcur, buf2);
  conv_kernel<<<1563, 256, 0, stream>>>(embed, xb);   // after part2: buf1 dead
  layer_kernel<0><<<NFINE, 512, 0, stream>>>(xb, W1, root1, b1, foff,
                                             buf2, h, out);
  layer_kernel<1><<<NFINE, 512, 0, stream>>>(h, W2, root2, b2, foff,
                                             buf2, h, out);
}

// Round 11
// 219.719 us; speedup vs baseline: 1.1208x; 1.1208x over previous
//
#include <hip/hip_runtime.h>

// RGCN 2-layer, N=100000, E=3200000, R=8, H=C=16.
// r11: fixed-capacity radix regions. init(cursors) -> part1 (coarse 49-way
// scatter into fixed 68608-slot regions) -> part2 (fine 32-way scatter per
// coarse slice into fixed 2304-slot regions) -> conv(embed->bf16) ->
// 2x layer. No histogram/scan kernels at all (6 dispatches total).
// Layer: Phase A (node,rel) counting sort in LDS; Phase B segmented sums via
// indicator-MFMA over 32-edge batches; Phase C 4 rel-block MFMAs + root MFMA
// + fused relu / log_softmax. All X gathers bf16 (L2-resident table).

constexpr int NN = 100000;
constexpr int NE = 3200000;
constexpr int NFINE = 1563;      // ceil(NN/64)
constexpr int NCOARSE = 49;      // ceil(NN/2048)
constexpr int NSLICE = 16;       // part2 slices per coarse segment
constexpr unsigned CAPC = 68608; // coarse region cap (mean 65536, +12 sigma)
constexpr unsigned CAPF = 2304;  // fine region cap (mean 2048, +5.7 sigma)
constexpr int CAP = 3072;        // layer LDS edge capacity (> CAPF)
constexpr int SST = 136;         // S node stride (ushorts); 272B rows, 16B-aligned

typedef short bf16x8 __attribute__((ext_vector_type(8)));
typedef float f32x4 __attribute__((ext_vector_type(4)));

__device__ __forceinline__ short f2bf(float f) {
  union { float f; unsigned u; } v; v.f = f;
  unsigned r = v.u + 0x7FFFu + ((v.u >> 16) & 1u);  // RNE
  return (short)(r >> 16);
}

// K0: region cursor init (replaces all histogram/scan kernels + memset).
__global__ void __launch_bounds__(256) init_kernel(
    unsigned* __restrict__ ccur, unsigned* __restrict__ fcur) {
  int i = blockIdx.x * 256 + threadIdx.x;
  if (i < NFINE) fcur[i] = (unsigned)i * CAPF;
  if (i < NCOARSE) ccur[i] = (unsigned)i * CAPC;
}

// K1: embed f32 -> bf16 table (once).
__global__ void __launch_bounds__(256) conv_kernel(
    const float* __restrict__ X, unsigned short* __restrict__ Xb) {
  int i = blockIdx.x * 256 + threadIdx.x;
  if (i < NN * 4) {
    float4 v = reinterpret_cast<const float4*>(X)[i];
    ushort4 o;
    o.x = (unsigned short)f2bf(v.x); o.y = (unsigned short)f2bf(v.y);
    o.z = (unsigned short)f2bf(v.z); o.w = (unsigned short)f2bf(v.w);
    reinterpret_cast<ushort4*>(Xb)[i] = o;
  }
}

// K2: coarse partition (dst>>11). Entry = src | rel<<17 | (dst&2047)<<20.
__global__ void __launch_bounds__(256) part1_kernel(
    const int* __restrict__ src, const int* __restrict__ dst,
    const int* __restrict__ typ, unsigned* __restrict__ ccur,
    unsigned* __restrict__ buf1) {
  __shared__ unsigned hist[NCOARSE];
  __shared__ unsigned gb[NCOARSE];
  if (threadIdx.x < NCOARSE) hist[threadIdx.x] = 0u;
  __syncthreads();
  const int base = blockIdx.x * 4096;
  unsigned ent[16], cb[16], rk[16];
#pragma unroll
  for (int i = 0; i < 16; ++i) {
    int e = base + i * 256 + threadIdx.x;
    if (e < NE) {
      unsigned d = (unsigned)dst[e];
      ent[i] = (unsigned)src[e] | ((unsigned)typ[e] << 17) | ((d & 2047u) << 20);
      cb[i] = d >> 11;
      rk[i] = atomicAdd(&hist[cb[i]], 1u);
    } else cb[i] = 0xFFFFFFFFu;
  }
  __syncthreads();
  if (threadIdx.x < NCOARSE && hist[threadIdx.x])
    gb[threadIdx.x] = atomicAdd(&ccur[threadIdx.x], hist[threadIdx.x]);
  __syncthreads();
#pragma unroll
  for (int i = 0; i < 16; ++i)
    if (cb[i] != 0xFFFFFFFFu) {
      unsigned pos = gb[cb[i]] + rk[i];
      if (pos < (cb[i] + 1u) * CAPC) buf1[pos] = ent[i];  // cap guard
    }
}

// K3: fine scatter, two passes over an L2-resident coarse slice.
// Pass1: 32-bin local hist + ONE fcur grab per bin. Pass2: re-read,
// LDS-rank, write low-26-bit entry into the fine bucket's fixed region.
__global__ void __launch_bounds__(256) part2_kernel(
    const unsigned* __restrict__ buf1, const unsigned* __restrict__ ccur,
    unsigned* __restrict__ fcur, unsigned* __restrict__ buf2) {
  __shared__ unsigned h[32], gb[32], cur[32];
  const int c = blockIdx.x >> 4, s = blockIdx.x & (NSLICE - 1);
  const unsigned b0 = (unsigned)c * CAPC;
  const unsigned len = ccur[c] - b0;
  const unsigned sl = (len + NSLICE - 1) / NSLICE;
  const unsigned lo = b0 + s * sl;
  unsigned hi = lo + sl;
  { unsigned b1 = b0 + len; if (hi > b1) hi = b1; }
  if (threadIdx.x < 32) { h[threadIdx.x] = 0u; cur[threadIdx.x] = 0u; }
  __syncthreads();
  for (unsigned p = lo + threadIdx.x; p < hi; p += 256)
    atomicAdd(&h[(buf1[p] >> 26) & 31u], 1u);
  __syncthreads();
  if (threadIdx.x < 32) {
    unsigned n = h[threadIdx.x];
    gb[threadIdx.x] = n ? atomicAdd(&fcur[c * 32 + threadIdx.x], n) : 0u;
  }
  __syncthreads();
  for (unsigned p = lo + threadIdx.x; p < hi; p += 256) {
    unsigned e = buf1[p];
    unsigned fl = (e >> 26) & 31u;
    unsigned f = (unsigned)c * 32u + fl;
    unsigned pos = gb[fl] + atomicAdd(&cur[fl], 1u);
    if (pos < (f + 1u) * CAPF) buf2[pos] = e & 0x03FFFFFFu;  // cap guard
  }
}

// K4/K5: per-bucket layer (identical to round 9/10 except fixed-region p0).
template <int MODE>
__global__ void __launch_bounds__(512) layer_kernel(
    const unsigned short* __restrict__ Xb, const float* __restrict__ W,
    const float* __restrict__ ROOT, const float* __restrict__ BIAS,
    const unsigned* __restrict__ fcur, const unsigned* __restrict__ buf2,
    unsigned short* __restrict__ Hout, float* __restrict__ Fout) {
  __shared__ unsigned short S[64 * SST];
  __shared__ unsigned E[CAP];
  __shared__ unsigned cnt512[512];
  __shared__ unsigned cur512[512];
  __shared__ unsigned wsum[8];
  const int tid = threadIdx.x;

  cnt512[tid] = 0u;
#pragma unroll
  for (int i = 0; i < CAP / 512; ++i) E[tid + i * 512] = 0u;
  __syncthreads();

  const unsigned p0 = (unsigned)blockIdx.x * CAPF;
  const int seg = (int)(fcur[blockIdx.x] - p0);

  unsigned e_0 = 0xFFFFFFFFu, e_1 = 0xFFFFFFFFu, e_2 = 0xFFFFFFFFu,
           e_3 = 0xFFFFFFFFu, e_4 = 0xFFFFFFFFu;
  if (tid < seg)          e_0 = buf2[p0 + tid];
  if (tid + 512 < seg)    e_1 = buf2[p0 + tid + 512];
  if (tid + 1024 < seg)   e_2 = buf2[p0 + tid + 1024];
  if (tid + 1536 < seg)   e_3 = buf2[p0 + tid + 1536];
  if (tid + 2048 < seg)   e_4 = buf2[p0 + tid + 2048];
  auto BIN = [](unsigned e) -> unsigned { return (e >> 17) & 511u; };
  auto HB = [&](unsigned e) {
    if (e != 0xFFFFFFFFu) atomicAdd(&cnt512[BIN(e)], 1u);
  };
  HB(e_0); HB(e_1); HB(e_2); HB(e_3); HB(e_4);
  __syncthreads();

  unsigned own = cnt512[tid];
  unsigned incl = own;
#pragma unroll
  for (int d = 1; d < 64; d <<= 1) {
    unsigned t = __shfl_up(incl, d, 64);
    if ((tid & 63) >= d) incl += t;
  }
  if ((tid & 63) == 63) wsum[tid >> 6] = incl;
  __syncthreads();
  unsigned pre = 0;
#pragma unroll
  for (int wv = 0; wv < 8; ++wv)
    pre += (wv < (tid >> 6)) ? wsum[wv] : 0u;
  cur512[tid] = pre + incl - own;
  __syncthreads();

  auto SC = [&](unsigned e) {
    if (e != 0xFFFFFFFFu) {
      unsigned pos = atomicAdd(&cur512[BIN(e)], 1u);
      if (pos < (unsigned)CAP) E[pos] = e;
    }
  };
  SC(e_0); SC(e_1); SC(e_2); SC(e_3); SC(e_4);
  __syncthreads();

  const int w = tid >> 6;
  const int lane = tid & 63;
  const int rc = lane & 15;
  const int quad = lane >> 4;

  for (int pq = 0; pq < 4; ++pq) {
    const int pp = w * 4 + pq;
    const int pb = pp * 16;
    const int beg = (int)(cur512[pb] - cnt512[pb]);
    const int end = (int)cur512[pb + 15];
    const unsigned rowbin = (unsigned)(pb + rc);

    f32x4 acc = {0.f, 0.f, 0.f, 0.f};
    int p = beg;
    for (; p + 32 <= end; p += 32) {
      bf16x8 af, bv;
#pragma unroll
      for (int j = 0; j < 8; ++j) {
        unsigned e = E[p + quad * 8 + j];
        af[j] = (((e >> 17) & 511u) == rowbin) ? (short)0x3F80 : (short)0;
        bv[j] = (short)Xb[(size_t)(e & 0x1FFFFu) * 16 + rc];
      }
      acc = __builtin_amdgcn_mfma_f32_16x16x32_bf16(af, bv, acc, 0, 0, 0);
    }
    if (p < end) {
      bf16x8 af, bv;
#pragma unroll
      for (int j = 0; j < 8; ++j) {
        int q = p + quad * 8 + j;
        unsigned e = E[q < CAP ? q : 0];
        bool v = q < end;
        af[j] = (v && ((e >> 17) & 511u) == rowbin) ? (short)0x3F80 : (short)0;
        bv[j] = (short)Xb[(size_t)(e & 0x1FFFFu) * 16 + rc];
      }
      acc = __builtin_amdgcn_mfma_f32_16x16x32_bf16(af, bv, acc, 0, 0, 0);
    }

#pragma unroll
    for (int r2 = 0; r2 < 4; ++r2) {
      int gbin = pb + quad * 4 + r2;
      unsigned ct = cnt512[gbin];
      float iv = 1.f / (float)(ct ? ct : 1u);
      int nd = gbin >> 3, rl = gbin & 7;
      S[nd * SST + rl * 16 + rc] = (unsigned short)f2bf(acc[r2] * iv);
    }
  }
  __syncthreads();

  if (w >= 4) return;
  const int fc = lane & 15;
  const int g = lane >> 4;
  const int n0 = blockIdx.x * 64 + w * 16;

  bf16x8 b0, b1, b2, b3, brt;
#pragma unroll
  for (int j = 0; j < 8; ++j) {
    int kq = g * 8 + j; int rb = kq >> 4; int kk = kq & 15;
    b0[j] = f2bf(W[(rb + 0) * 256 + kk * 16 + fc]);
    b1[j] = f2bf(W[(rb + 2) * 256 + kk * 16 + fc]);
    b2[j] = f2bf(W[(rb + 4) * 256 + kk * 16 + fc]);
    b3[j] = f2bf(W[(rb + 6) * 256 + kk * 16 + fc]);
    brt[j] = (kq < 16) ? f2bf(ROOT[kq * 16 + fc]) : (short)0;
  }

  const int kk0 = (g & 1) * 8;
  const int rsel = g >> 1;
  const int dl16 = w * 16 + fc;
  bf16x8 a0, a1, a2, a3;
#define LDA(AM, M)                                                        \
  {                                                                       \
    const unsigned short* sp2 = S + dl16 * SST + (2 * (M) + rsel) * 16 + kk0; \
    AM = *reinterpret_cast<const bf16x8*>(sp2);                           \
  }
  LDA(a0, 0) LDA(a1, 1) LDA(a2, 2) LDA(a3, 3)
#undef LDA

  bf16x8 ar = {0, 0, 0, 0, 0, 0, 0, 0};
  if (g < 2) {
    int node = n0 + fc;
    if (node < NN)
      ar = *reinterpret_cast<const bf16x8*>(Xb + (size_t)node * 16 + g * 8);
  }

  const float bc = BIAS[fc];
  f32x4 acc = {bc, bc, bc, bc};
  acc = __builtin_amdgcn_mfma_f32_16x16x32_bf16(a0, b0, acc, 0, 0, 0);
  acc = __builtin_amdgcn_mfma_f32_16x16x32_bf16(a1, b1, acc, 0, 0, 0);
  acc = __builtin_amdgcn_mfma_f32_16x16x32_bf16(a2, b2, acc, 0, 0, 0);
  acc = __builtin_amdgcn_mfma_f32_16x16x32_bf16(a3, b3, acc, 0, 0, 0);
  acc = __builtin_amdgcn_mfma_f32_16x16x32_bf16(ar, brt, acc, 0, 0, 0);

  if (MODE == 0) {
#pragma unroll
    for (int r2 = 0; r2 < 4; ++r2) {
      int node = n0 + g * 4 + r2;
      if (node < NN)
        Hout[(size_t)node * 16 + fc] = (unsigned short)f2bf(fmaxf(acc[r2], 0.f));
    }
  } else {
#pragma unroll
    for (int r2 = 0; r2 < 4; ++r2) {
      int node = n0 + g * 4 + r2;
      float zv = acc[r2];
      float mx = zv;
      mx = fmaxf(mx, __shfl_xor(mx, 1));
      mx = fmaxf(mx, __shfl_xor(mx, 2));
      mx = fmaxf(mx, __shfl_xor(mx, 4));
      mx = fmaxf(mx, __shfl_xor(mx, 8));
      float sm = expf(zv - mx);
      sm += __shfl_xor(sm, 1);
      sm += __shfl_xor(sm, 2);
      sm += __shfl_xor(sm, 4);
      sm += __shfl_xor(sm, 8);
      if (node < NN)
        Fout[(size_t)node * 16 + fc] = zv - mx - logf(sm);
    }
  }
}

extern "C" void kernel_launch(void* const* d_in, const int* in_sizes, int n_in,
                              void* d_out, int out_size, void* d_ws, size_t ws_size,
                              hipStream_t stream) {
  const float* embed = (const float*)d_in[0];
  const float* W1    = (const float*)d_in[1];
  const float* root1 = (const float*)d_in[2];
  const float* b1    = (const float*)d_in[3];
  const float* W2    = (const float*)d_in[4];
  const float* root2 = (const float*)d_in[5];
  const float* b2    = (const float*)d_in[6];
  const int* eidx    = (const int*)d_in[7];
  const int* etyp    = (const int*)d_in[8];
  const int* src = eidx;
  const int* dst = eidx + NE;
  float* out = (float*)d_out;

  // ws (u32): ccur[64] fcur[1600] buf1[49*CAPC] buf2[1563*CAPF]  (~27.9 MB)
  // buf1 (dead after part2) hosts h (bf16, first 800K u32) and xb (bf16
  // embed, next 800K u32); remaining space is scratch.
  unsigned* ccur = (unsigned*)d_ws;
  unsigned* fcur = ccur + 64;
  unsigned* buf1 = fcur + 1600;
  unsigned* buf2 = buf1 + (size_t)NCOARSE * CAPC;
  unsigned short* h  = (unsigned short*)buf1;
  unsigned short* xb = (unsigned short*)(buf1 + 800000);

  init_kernel<<<7, 256, 0, stream>>>(ccur, fcur);
  part1_kernel<<<782, 256, 0, stream>>>(src, dst, etyp, ccur, buf1);
  part2_kernel<<<NCOARSE * NSLICE, 256, 0, stream>>>(buf1, ccur, fcur, buf2);
  conv_kernel<<<1563, 256, 0, stream>>>(embed, xb);   // buf1 payload dead now
  layer_kernel<0><<<NFINE, 512, 0, stream>>>(xb, W1, root1, b1, fcur,
                                             buf2, h, out);
  layer_kernel<1><<<NFINE, 512, 0, stream>>>(h, W2, root2, b2, fcur,
                                             buf2, h, out);
}